// Round 2
// baseline (87.249 us; speedup 1.0000x reference)
//
#include <hip/hip_runtime.h>
#include <hip/hip_cooperative_groups.h>
#include <math.h>

namespace cg = cooperative_groups;

// noises [L=12, N=4096, D=16] fp32. Loss factorizes:
//   ce.sum()  = sum_l sum_d (sum_i p[l,i,d]) * (sum_j log_q[l,j,d])
//   diag_sum  = sum_{l,i,d} p*log_q   (per-row dot)
//   aux2 needs only sum_i p[l,i,d]
// Budget: harness re-poisons the 256 MiB workspace every iteration
// (~40.6 us fill, stream-ordered before us) — invariant. The remaining
// ~19 us tail was dispatch structure (2 kernel nodes + gap). This
// version fuses both passes into ONE cooperative kernel:
//   192 blocks x 256 threads (1 row/thread), butterfly wave reduction
//   (17 shuffles per 16-array), LDS cross-wave combine, value-major
//   partials part[33][192], grid.sync(), block 0 finalizes (each (l,d)
//   thread reads 16 contiguous partials = 4 float4s).
#define LAYERS 12
#define NROWS  4096
#define DDIM   16
#define BLOCK  256
#define NBLK   192                          // 16 blocks per layer
#define BPL    16                           // blocks per layer
#define PART   33                           // 16 sumP + 16 sumLQ + 1 diag

__device__ __forceinline__ float wave_red6(float v) {
    #pragma unroll
    for (int off = 32; off > 0; off >>= 1)
        v += __shfl_xor(v, off, 64);
    return v;
}

// Halving butterfly: v[16] per lane, 64 lanes. Returns, in EVERY lane,
// the full 64-lane sum of v[d] for d = lane>>2.
// 8+4+2+1 shuffles to 1 value/lane, +2 to fold the 4-lane redundancy:
// 17 shuffles total vs 96 for per-scalar trees.
__device__ __forceinline__ float red16(const float* v, int lane) {
    const bool b5 = lane & 32, b4 = lane & 16, b3 = lane & 8, b2 = lane & 4;
    float w8[8], w4[4], w2[2], w1;
    #pragma unroll
    for (int k = 0; k < 8; k++) {
        float t = b5 ? v[k] : v[k + 8];          // send what partner keeps
        float o = __shfl_xor(t, 32, 64);
        w8[k] = (b5 ? v[k + 8] : v[k]) + o;      // keep own half + partner's
    }
    #pragma unroll
    for (int k = 0; k < 4; k++) {
        float t = b4 ? w8[k] : w8[k + 4];
        float o = __shfl_xor(t, 16, 64);
        w4[k] = (b4 ? w8[k + 4] : w8[k]) + o;
    }
    #pragma unroll
    for (int k = 0; k < 2; k++) {
        float t = b3 ? w4[k] : w4[k + 2];
        float o = __shfl_xor(t, 8, 64);
        w2[k] = (b3 ? w4[k + 2] : w4[k]) + o;
    }
    {
        float t = b2 ? w2[0] : w2[1];
        float o = __shfl_xor(t, 4, 64);
        w1 = (b2 ? w2[1] : w2[0]) + o;
    }
    w1 += __shfl_xor(w1, 2, 64);
    w1 += __shfl_xor(w1, 1, 64);
    return w1;   // d = lane>>2
}

__global__ __launch_bounds__(BLOCK)
void moe_loss_fused(const float* __restrict__ x, float* __restrict__ part,
                    float* __restrict__ out) {
    const int tid  = threadIdx.x;
    const int b    = blockIdx.x;            // 16 consecutive blocks per layer
    const int wave = tid >> 6;
    const int lane = tid & 63;

    // ---- phase 1: per-row softmax stats (1 row = 16 floats per thread) ----
    const float4* x4 = (const float4*)x;
    const int r4 = (b * BLOCK + tid) * 4;
    float v[DDIM]; float4 a4;
    a4 = x4[r4 + 0]; v[0]  = a4.x; v[1]  = a4.y; v[2]  = a4.z; v[3]  = a4.w;
    a4 = x4[r4 + 1]; v[4]  = a4.x; v[5]  = a4.y; v[6]  = a4.z; v[7]  = a4.w;
    a4 = x4[r4 + 2]; v[8]  = a4.x; v[9]  = a4.y; v[10] = a4.z; v[11] = a4.w;
    a4 = x4[r4 + 3]; v[12] = a4.x; v[13] = a4.y; v[14] = a4.z; v[15] = a4.w;

    float m = v[0];
    #pragma unroll
    for (int d = 1; d < DDIM; d++) m = fmaxf(m, v[d]);
    float e[DDIM], s = 0.f;
    #pragma unroll
    for (int d = 0; d < DDIM; d++) { e[d] = __expf(v[d] - m); s += e[d]; }
    const float inv = __frcp_rn(s);

    float p[DDIM], lq[DDIM], diag = 0.f;
    #pragma unroll
    for (int d = 0; d < DDIM; d++) {
        p[d]  = e[d] * inv;
        lq[d] = __logf(p[d] + 1e-9f);
        diag += p[d] * lq[d];
    }

    const float sp = red16(p,  lane);   // wave sum of p[lane>>2]
    const float sl = red16(lq, lane);   // wave sum of lq[lane>>2]
    const float dg = wave_red6(diag);   // wave sum of diag

    // ---- cross-wave combine -> value-major partials part[v*192 + b] ----
    __shared__ float lds[BLOCK / 64][PART];
    {
        const int g = lane >> 2, sub = lane & 3;
        if (sub == 0) lds[wave][g] = sp;
        if (sub == 1) lds[wave][DDIM + g] = sl;
        if (lane == 2) lds[wave][32] = dg;
    }
    __syncthreads();
    if (tid < PART)
        part[tid * NBLK + b] = lds[0][tid] + lds[1][tid] + lds[2][tid] + lds[3][tid];

    cg::this_grid().sync();

    // ---- phase 2: block 0 finalizes ----
    if (b != 0) return;

    __shared__ float sP[LAYERS][DDIM];
    const int l = tid >> 4, d = tid & 15;
    float a = 0.f, bq = 0.f;
    if (tid < LAYERS * DDIM) {
        // per (l,d): 16 contiguous partials -> 4 float4 loads each
        const float4* pa = (const float4*)(part + d * NBLK + l * BPL);
        const float4* pb = (const float4*)(part + (DDIM + d) * NBLK + l * BPL);
        #pragma unroll
        for (int k = 0; k < BPL / 4; k++) {
            float4 va = pa[k]; a  += va.x + va.y + va.z + va.w;
            float4 vb = pb[k]; bq += vb.x + vb.y + vb.z + vb.w;
        }
        sP[l][d] = a;
    }
    __syncthreads();
    float ce_v = 0.f, lg_v = 0.f;
    if (tid < LAYERS * DDIM) {
        float S = 0.f;
        #pragma unroll
        for (int d2 = 0; d2 < DDIM; d2++) S += sP[l][d2];
        ce_v = a * bq;                        // -> ce.sum()
        lg_v = __logf(a / S + 1e-8f);         // -> aux2 (pm = a/S)
    }
    const float dg_v = (tid < NBLK) ? part[32 * NBLK + tid] : 0.f;

    __shared__ float red[3][BLOCK / 64];
    const float r0 = wave_red6(ce_v), r1 = wave_red6(lg_v), r2 = wave_red6(dg_v);
    if (lane == 0) { red[0][wave] = r0; red[1][wave] = r1; red[2][wave] = r2; }
    __syncthreads();
    if (tid == 0) {
        const float ce = red[0][0] + red[0][1] + red[0][2] + red[0][3];
        const float lg = red[1][0] + red[1][1] + red[1][2] + red[1][3];
        const float dg = red[2][0] + red[2][1] + red[2][2] + red[2][3];
        const float aux1 = (ce - dg) / (2.0f * LAYERS);
        const float aux2 = (-lg / (float)DDIM) / (float)LAYERS;
        out[0] = 0.01f * (1.0f * aux1 + aux2);
    }
}

extern "C" void kernel_launch(void* const* d_in, const int* in_sizes, int n_in,
                              void* d_out, int out_size, void* d_ws, size_t ws_size,
                              hipStream_t stream) {
    const float* noises = (const float*)d_in[0];
    float* part = (float*)d_ws;                 // 33*192*4 = 25,344 B scratch
    float* out  = (float*)d_out;
    void* args[] = { (void*)&noises, (void*)&part, (void*)&out };
    hipLaunchCooperativeKernel((const void*)moe_loss_fused,
                               dim3(NBLK), dim3(BLOCK), args, 0, stream);
}

// Round 3
// 68.685 us; speedup vs baseline: 1.2703x; 1.2703x over previous
//
#include <hip/hip_runtime.h>
#include <math.h>

// noises [L=12, N=4096, D=16] fp32. Loss factorizes:
//   ce.sum()  = sum_l sum_d (sum_i p[l,i,d]) * (sum_j log_q[l,j,d])
//   diag_sum  = sum_{l,i,d} p*log_q   (per-row dot)
//   aux2 needs only sum_i p[l,i,d]
// Budget: harness re-poisons the 256 MiB workspace every iteration
// (~40.6 us fill, stream-ordered first) — invariant. r1 (two kernel
// nodes) had an 18.9 us tail; r2's cooperative fuse cost +28 us (coop
// launch machinery). This version fuses into ONE PLAIN kernel node:
//   - 192 blocks x 256 threads, phase 1 identical to r1/r2 (butterfly
//     wave reduce, LDS combine, value-major partials part[33][192]).
//   - partials stored with agent-scope atomics; per-block ready-flag
//     PAIR (A = 0x5EED0000^b, B = ~A). No poison word can satisfy
//     A==exp && B==~exp (needs P==~P) -> init-free, poison-proof.
//   - block 0 spins (bounded) on the 192 flag pairs, then finalizes.
// No cooperative launch, no counter memset, no second dispatch.
#define LAYERS 12
#define NROWS  4096
#define DDIM   16
#define BLOCK  256
#define NBLK   192                          // 16 blocks per layer
#define BPL    16                           // blocks per layer
#define PART   33                           // 16 sumP + 16 sumLQ + 1 diag
#define FLAG_OFF 6400                       // floats; 25,600 B, past partials
#define SPIN_CAP 2000000                    // ~degrade, never hang

__device__ __forceinline__ float wave_red6(float v) {
    #pragma unroll
    for (int off = 32; off > 0; off >>= 1)
        v += __shfl_xor(v, off, 64);
    return v;
}

// Halving butterfly: v[16] per lane, 64 lanes. Returns, in EVERY lane,
// the full 64-lane sum of v[d] for d = lane>>2. 17 shuffles vs 96.
__device__ __forceinline__ float red16(const float* v, int lane) {
    const bool b5 = lane & 32, b4 = lane & 16, b3 = lane & 8, b2 = lane & 4;
    float w8[8], w4[4], w2[2], w1;
    #pragma unroll
    for (int k = 0; k < 8; k++) {
        float t = b5 ? v[k] : v[k + 8];
        float o = __shfl_xor(t, 32, 64);
        w8[k] = (b5 ? v[k + 8] : v[k]) + o;
    }
    #pragma unroll
    for (int k = 0; k < 4; k++) {
        float t = b4 ? w8[k] : w8[k + 4];
        float o = __shfl_xor(t, 16, 64);
        w4[k] = (b4 ? w8[k + 4] : w8[k]) + o;
    }
    #pragma unroll
    for (int k = 0; k < 2; k++) {
        float t = b3 ? w4[k] : w4[k + 2];
        float o = __shfl_xor(t, 8, 64);
        w2[k] = (b3 ? w4[k + 2] : w4[k]) + o;
    }
    {
        float t = b2 ? w2[0] : w2[1];
        float o = __shfl_xor(t, 4, 64);
        w1 = (b2 ? w2[1] : w2[0]) + o;
    }
    w1 += __shfl_xor(w1, 2, 64);
    w1 += __shfl_xor(w1, 1, 64);
    return w1;   // d = lane>>2
}

__global__ __launch_bounds__(BLOCK)
void moe_loss_fused(const float* __restrict__ x, float* __restrict__ ws,
                    float* __restrict__ out) {
    const int tid  = threadIdx.x;
    const int b    = blockIdx.x;            // 16 consecutive blocks per layer
    const int wave = tid >> 6;
    const int lane = tid & 63;
    float* part = ws;
    unsigned int* flagA = (unsigned int*)(ws + FLAG_OFF);
    unsigned int* flagB = flagA + 256;      // padded apart

    // ---- phase 1: per-row softmax stats (1 row = 16 floats/thread) ----
    const float4* x4 = (const float4*)x;
    const int r4 = (b * BLOCK + tid) * 4;
    float v[DDIM]; float4 a4;
    a4 = x4[r4 + 0]; v[0]  = a4.x; v[1]  = a4.y; v[2]  = a4.z; v[3]  = a4.w;
    a4 = x4[r4 + 1]; v[4]  = a4.x; v[5]  = a4.y; v[6]  = a4.z; v[7]  = a4.w;
    a4 = x4[r4 + 2]; v[8]  = a4.x; v[9]  = a4.y; v[10] = a4.z; v[11] = a4.w;
    a4 = x4[r4 + 3]; v[12] = a4.x; v[13] = a4.y; v[14] = a4.z; v[15] = a4.w;

    float m = v[0];
    #pragma unroll
    for (int d = 1; d < DDIM; d++) m = fmaxf(m, v[d]);
    float e[DDIM], s = 0.f;
    #pragma unroll
    for (int d = 0; d < DDIM; d++) { e[d] = __expf(v[d] - m); s += e[d]; }
    const float inv = __frcp_rn(s);

    float p[DDIM], lq[DDIM], diag = 0.f;
    #pragma unroll
    for (int d = 0; d < DDIM; d++) {
        p[d]  = e[d] * inv;
        lq[d] = __logf(p[d] + 1e-9f);
        diag += p[d] * lq[d];
    }

    const float sp = red16(p,  lane);
    const float sl = red16(lq, lane);
    const float dg = wave_red6(diag);

    // ---- cross-wave combine -> value-major partials part[v*192 + b] ----
    __shared__ float lds[BLOCK / 64][PART];
    {
        const int g = lane >> 2, sub = lane & 3;
        if (sub == 0) lds[wave][g] = sp;
        if (sub == 1) lds[wave][DDIM + g] = sl;
        if (lane == 2) lds[wave][32] = dg;
    }
    __syncthreads();
    if (tid < PART) {
        const float val = lds[0][tid] + lds[1][tid] + lds[2][tid] + lds[3][tid];
        // agent-scope store: device-visible past the per-XCD L2
        __hip_atomic_store(&part[tid * NBLK + b], val,
                           __ATOMIC_RELEASE, __HIP_MEMORY_SCOPE_AGENT);
    }
    __syncthreads();          // implicit vmcnt(0): partial stores committed
    if (tid == 0) {
        __threadfence();
        const unsigned int seq = 0x5EED0000u ^ (unsigned int)b;
        __hip_atomic_store(&flagA[b], seq,  __ATOMIC_RELEASE, __HIP_MEMORY_SCOPE_AGENT);
        __hip_atomic_store(&flagB[b], ~seq, __ATOMIC_RELEASE, __HIP_MEMORY_SCOPE_AGENT);
    }

    if (b != 0) return;

    // ---- phase 2: block 0 waits for all flags, then finalizes ----
    if (tid < NBLK) {
        const unsigned int expA = 0x5EED0000u ^ (unsigned int)tid;
        const unsigned int expB = ~expA;
        int it = 0;
        for (;;) {
            const unsigned int fa = __hip_atomic_load(&flagA[tid],
                                    __ATOMIC_ACQUIRE, __HIP_MEMORY_SCOPE_AGENT);
            const unsigned int fb = __hip_atomic_load(&flagB[tid],
                                    __ATOMIC_ACQUIRE, __HIP_MEMORY_SCOPE_AGENT);
            if (fa == expA && fb == expB) break;
            if (++it > SPIN_CAP) break;     // degrade, never hang
            __builtin_amdgcn_s_sleep(1);
        }
    }
    __syncthreads();

    __shared__ float sP[LAYERS][DDIM];
    const int l = tid >> 4, d = tid & 15;
    float a = 0.f, bq = 0.f;
    if (tid < LAYERS * DDIM) {
        // per (l,d): 16 contiguous partials each; coherent loads
        const float* pa = part + d * NBLK + l * BPL;
        const float* pb = part + (DDIM + d) * NBLK + l * BPL;
        #pragma unroll
        for (int k = 0; k < BPL; k++) {
            a  += __hip_atomic_load(&pa[k], __ATOMIC_RELAXED, __HIP_MEMORY_SCOPE_AGENT);
            bq += __hip_atomic_load(&pb[k], __ATOMIC_RELAXED, __HIP_MEMORY_SCOPE_AGENT);
        }
        sP[l][d] = a;
    }
    __syncthreads();
    float ce_v = 0.f, lg_v = 0.f;
    if (tid < LAYERS * DDIM) {
        float S = 0.f;
        #pragma unroll
        for (int d2 = 0; d2 < DDIM; d2++) S += sP[l][d2];
        ce_v = a * bq;                        // -> ce.sum()
        lg_v = __logf(a / S + 1e-8f);         // -> aux2 (pm = a/S)
    }
    const float dg_v = (tid < NBLK)
        ? __hip_atomic_load(&part[32 * NBLK + tid], __ATOMIC_RELAXED,
                            __HIP_MEMORY_SCOPE_AGENT)
        : 0.f;

    __shared__ float red[3][BLOCK / 64];
    const float r0 = wave_red6(ce_v), r1 = wave_red6(lg_v), r2 = wave_red6(dg_v);
    if (lane == 0) { red[0][wave] = r0; red[1][wave] = r1; red[2][wave] = r2; }
    __syncthreads();
    if (tid == 0) {
        const float ce = red[0][0] + red[0][1] + red[0][2] + red[0][3];
        const float lg = red[1][0] + red[1][1] + red[1][2] + red[1][3];
        const float dgs = red[2][0] + red[2][1] + red[2][2] + red[2][3];
        const float aux1 = (ce - dgs) / (2.0f * LAYERS);
        const float aux2 = (-lg / (float)DDIM) / (float)LAYERS;
        out[0] = 0.01f * (1.0f * aux1 + aux2);
    }
}

extern "C" void kernel_launch(void* const* d_in, const int* in_sizes, int n_in,
                              void* d_out, int out_size, void* d_ws, size_t ws_size,
                              hipStream_t stream) {
    const float* noises = (const float*)d_in[0];
    float* ws  = (float*)d_ws;                  // ~26.6 KB used
    float* out = (float*)d_out;
    hipLaunchKernelGGL(moe_loss_fused, dim3(NBLK), dim3(BLOCK), 0, stream,
                       noises, ws, out);
}

// Round 4
// 62.617 us; speedup vs baseline: 1.3934x; 1.0969x over previous
//
#include <hip/hip_runtime.h>
#include <math.h>

// noises [L=12, N=4096, D=16] fp32. Loss factorizes:
//   ce.sum()  = sum_l sum_d (sum_i p[l,i,d]) * (sum_j log_q[l,j,d])
//   diag_sum  = sum_{l,i,d} p*log_q   (per-row dot)
//   aux2 needs only sum_i p[l,i,d]
// Budget: harness re-poisons the 256 MiB workspace every iteration
// (~40.6 us fill, stream-ordered first) — invariant. History:
//   r1 two plain nodes: 59.45 (tail 18.9)
//   r2 cooperative fuse: 87.2 (coop launch machinery — dead end)
//   r3 fused + ACQ/REL atomics: 68.7 (per-store waitcnt + per-spin
//      buffer_inv cache ops — the plumbing, not the structure)
// r4: same fused structure, minimal sync plumbing:
//   - partials/flags: RELAXED agent atomics (global_store sc0 sc1,
//     write-through, NO per-op cache maintenance)
//   - ONE __threadfence per block (tid 0, post-barrier) orders
//     partials before the poison-proof flag pair (A=0x5EED^b, B=~A;
//     no single poison word satisfies both).
//   - block 0 spins with RELAXED loads (no buffer_inv per iter),
//     one fence after the spin, then finalizes.
#define LAYERS 12
#define NROWS  4096
#define DDIM   16
#define BLOCK  256
#define NBLK   192                          // 16 blocks per layer
#define BPL    16                           // blocks per layer
#define PART   33                           // 16 sumP + 16 sumLQ + 1 diag
#define FLAG_OFF 6400                       // floats; past partials (25,344 B)
#define SPIN_CAP 2000000                    // degrade, never hang

__device__ __forceinline__ float wave_red6(float v) {
    #pragma unroll
    for (int off = 32; off > 0; off >>= 1)
        v += __shfl_xor(v, off, 64);
    return v;
}

// Halving butterfly: v[16] per lane, 64 lanes. Returns, in EVERY lane,
// the full 64-lane sum of v[d] for d = lane>>2. 17 shuffles vs 96.
__device__ __forceinline__ float red16(const float* v, int lane) {
    const bool b5 = lane & 32, b4 = lane & 16, b3 = lane & 8, b2 = lane & 4;
    float w8[8], w4[4], w2[2], w1;
    #pragma unroll
    for (int k = 0; k < 8; k++) {
        float t = b5 ? v[k] : v[k + 8];
        float o = __shfl_xor(t, 32, 64);
        w8[k] = (b5 ? v[k + 8] : v[k]) + o;
    }
    #pragma unroll
    for (int k = 0; k < 4; k++) {
        float t = b4 ? w8[k] : w8[k + 4];
        float o = __shfl_xor(t, 16, 64);
        w4[k] = (b4 ? w8[k + 4] : w8[k]) + o;
    }
    #pragma unroll
    for (int k = 0; k < 2; k++) {
        float t = b3 ? w4[k] : w4[k + 2];
        float o = __shfl_xor(t, 8, 64);
        w2[k] = (b3 ? w4[k + 2] : w4[k]) + o;
    }
    {
        float t = b2 ? w2[0] : w2[1];
        float o = __shfl_xor(t, 4, 64);
        w1 = (b2 ? w2[1] : w2[0]) + o;
    }
    w1 += __shfl_xor(w1, 2, 64);
    w1 += __shfl_xor(w1, 1, 64);
    return w1;   // d = lane>>2
}

__device__ __forceinline__ void st_rlx(float* p, float v) {
    __hip_atomic_store(p, v, __ATOMIC_RELAXED, __HIP_MEMORY_SCOPE_AGENT);
}
__device__ __forceinline__ float ld_rlx(const float* p) {
    return __hip_atomic_load(p, __ATOMIC_RELAXED, __HIP_MEMORY_SCOPE_AGENT);
}
__device__ __forceinline__ void st_rlx_u(unsigned int* p, unsigned int v) {
    __hip_atomic_store(p, v, __ATOMIC_RELAXED, __HIP_MEMORY_SCOPE_AGENT);
}
__device__ __forceinline__ unsigned int ld_rlx_u(const unsigned int* p) {
    return __hip_atomic_load(p, __ATOMIC_RELAXED, __HIP_MEMORY_SCOPE_AGENT);
}

__global__ __launch_bounds__(BLOCK)
void moe_loss_fused(const float* __restrict__ x, float* __restrict__ ws,
                    float* __restrict__ out) {
    const int tid  = threadIdx.x;
    const int b    = blockIdx.x;            // 16 consecutive blocks per layer
    const int wave = tid >> 6;
    const int lane = tid & 63;
    float* part = ws;
    unsigned int* flagA = (unsigned int*)(ws + FLAG_OFF);
    unsigned int* flagB = flagA + 256;      // separate line region

    // ---- phase 1: per-row softmax stats (1 row = 16 floats/thread) ----
    const float4* x4 = (const float4*)x;
    const int r4 = (b * BLOCK + tid) * 4;
    float v[DDIM]; float4 a4;
    a4 = x4[r4 + 0]; v[0]  = a4.x; v[1]  = a4.y; v[2]  = a4.z; v[3]  = a4.w;
    a4 = x4[r4 + 1]; v[4]  = a4.x; v[5]  = a4.y; v[6]  = a4.z; v[7]  = a4.w;
    a4 = x4[r4 + 2]; v[8]  = a4.x; v[9]  = a4.y; v[10] = a4.z; v[11] = a4.w;
    a4 = x4[r4 + 3]; v[12] = a4.x; v[13] = a4.y; v[14] = a4.z; v[15] = a4.w;

    float m = v[0];
    #pragma unroll
    for (int d = 1; d < DDIM; d++) m = fmaxf(m, v[d]);
    float e[DDIM], s = 0.f;
    #pragma unroll
    for (int d = 0; d < DDIM; d++) { e[d] = __expf(v[d] - m); s += e[d]; }
    const float inv = __frcp_rn(s);

    float p[DDIM], lq[DDIM], diag = 0.f;
    #pragma unroll
    for (int d = 0; d < DDIM; d++) {
        p[d]  = e[d] * inv;
        lq[d] = __logf(p[d] + 1e-9f);
        diag += p[d] * lq[d];
    }

    const float sp = red16(p,  lane);
    const float sl = red16(lq, lane);
    const float dg = wave_red6(diag);

    // ---- cross-wave combine -> value-major partials part[v*192 + b] ----
    __shared__ float lds[BLOCK / 64][PART];
    {
        const int g = lane >> 2, sub = lane & 3;
        if (sub == 0) lds[wave][g] = sp;
        if (sub == 1) lds[wave][DDIM + g] = sl;
        if (lane == 2) lds[wave][32] = dg;
    }
    __syncthreads();
    if (tid < PART) {
        const float val = lds[0][tid] + lds[1][tid] + lds[2][tid] + lds[3][tid];
        st_rlx(&part[tid * NBLK + b], val);   // relaxed: plain sc0/sc1 store
    }
    __syncthreads();            // each wave drains vmcnt before barrier
    if (tid == 0) {
        __threadfence();        // one fence/block: partials before flags
        const unsigned int seq = 0x5EED0000u ^ (unsigned int)b;
        st_rlx_u(&flagA[b], seq);
        st_rlx_u(&flagB[b], ~seq);
    }

    if (b != 0) return;

    // ---- phase 2: block 0 waits on flag pairs, then finalizes ----
    if (tid < NBLK) {
        const unsigned int expA = 0x5EED0000u ^ (unsigned int)tid;
        const unsigned int expB = ~expA;
        int it = 0;
        for (;;) {
            const unsigned int fa = ld_rlx_u(&flagA[tid]);   // no cache ops
            const unsigned int fb = ld_rlx_u(&flagB[tid]);
            if (fa == expA && fb == expB) break;
            if (++it > SPIN_CAP) break;     // degrade, never hang
            __builtin_amdgcn_s_sleep(1);
        }
    }
    __syncthreads();
    __threadfence();            // one fence after spin, before partial reads

    __shared__ float sP[LAYERS][DDIM];
    const int l = tid >> 4, d = tid & 15;
    float a = 0.f, bq = 0.f;
    if (tid < LAYERS * DDIM) {
        const float* pa = part + d * NBLK + l * BPL;
        const float* pb = part + (DDIM + d) * NBLK + l * BPL;
        #pragma unroll
        for (int k = 0; k < BPL; k++) {
            a  += ld_rlx(&pa[k]);
            bq += ld_rlx(&pb[k]);
        }
        sP[l][d] = a;
    }
    __syncthreads();
    float ce_v = 0.f, lg_v = 0.f;
    if (tid < LAYERS * DDIM) {
        float S = 0.f;
        #pragma unroll
        for (int d2 = 0; d2 < DDIM; d2++) S += sP[l][d2];
        ce_v = a * bq;                        // -> ce.sum()
        lg_v = __logf(a / S + 1e-8f);         // -> aux2 (pm = a/S)
    }
    const float dg_v = (tid < NBLK) ? ld_rlx(&part[32 * NBLK + tid]) : 0.f;

    __shared__ float red[3][BLOCK / 64];
    const float r0 = wave_red6(ce_v), r1 = wave_red6(lg_v), r2 = wave_red6(dg_v);
    if (lane == 0) { red[0][wave] = r0; red[1][wave] = r1; red[2][wave] = r2; }
    __syncthreads();
    if (tid == 0) {
        const float ce = red[0][0] + red[0][1] + red[0][2] + red[0][3];
        const float lg = red[1][0] + red[1][1] + red[1][2] + red[1][3];
        const float dgs = red[2][0] + red[2][1] + red[2][2] + red[2][3];
        const float aux1 = (ce - dgs) / (2.0f * LAYERS);
        const float aux2 = (-lg / (float)DDIM) / (float)LAYERS;
        out[0] = 0.01f * (1.0f * aux1 + aux2);
    }
}

extern "C" void kernel_launch(void* const* d_in, const int* in_sizes, int n_in,
                              void* d_out, int out_size, void* d_ws, size_t ws_size,
                              hipStream_t stream) {
    const float* noises = (const float*)d_in[0];
    float* ws  = (float*)d_ws;                  // ~27 KB used
    float* out = (float*)d_out;
    hipLaunchKernelGGL(moe_loss_fused, dim3(NBLK), dim3(BLOCK), 0, stream,
                       noises, ws, out);
}

// Round 5
// 58.973 us; speedup vs baseline: 1.4795x; 1.0618x over previous
//
#include <hip/hip_runtime.h>
#include <math.h>

// noises [L=12, N=4096, D=16] fp32. Loss factorizes:
//   ce.sum()  = sum_l sum_d (sum_i p[l,i,d]) * (sum_j log_q[l,j,d])
//   diag_sum  = sum_{l,i,d} p*log_q   (per-row dot)
//   aux2 needs only sum_i p[l,i,d]
// Budget: harness re-poisons the 256 MiB workspace every iteration
// (~40.6 us fill, stream-ordered first) — invariant. History:
//   r1 two plain nodes:            59.45 us (tail 18.9)
//   r2 cooperative fuse:           87.2  us (coop machinery — dead end)
//   r3 fused, ACQ/REL everywhere:  68.7  us (per-op cache maintenance)
//   r4 fused, relaxed + 2 fences:  62.6  us (fences = buffer_wbl2/inv
//      forcing writeback of the fill's dirty L2 lines onto our path)
// r5: fused, ZERO fences / zero cache-maintenance ops:
//   - wave 0 stores the 33 partials (relaxed agent sc1 stores: acked
//     at the coherence point when vmcnt retires), then executes an
//     explicit s_waitcnt vmcnt(0), then lane 0 publishes ONE 64-bit
//     flag (lo=0x5EED0000^b, hi=~lo). Ordering by vmcnt only.
//   - poison-proof: a repeated 32-bit fill pattern can never satisfy
//     hi == ~lo; readiness needs no initialization.
//   - block 0 spins on a single 8B relaxed load per block, then reads
//     partials with relaxed agent loads (straight from the coherence
//     point; no stale-L2 consultation, no invalidate).
#define LAYERS 12
#define NROWS  4096
#define DDIM   16
#define BLOCK  256
#define NBLK   192                          // 16 blocks per layer
#define BPL    16                           // blocks per layer
#define PART   33                           // 16 sumP + 16 sumLQ + 1 diag
#define FLAG_OFF 6400                       // floats; byte 25600, 8B-aligned
#define SPIN_CAP 2000000                    // degrade, never hang

typedef unsigned long long ull;

__device__ __forceinline__ float wave_red6(float v) {
    #pragma unroll
    for (int off = 32; off > 0; off >>= 1)
        v += __shfl_xor(v, off, 64);
    return v;
}

// Halving butterfly: v[16] per lane, 64 lanes. Returns, in EVERY lane,
// the full 64-lane sum of v[d] for d = lane>>2. 17 shuffles vs 96.
__device__ __forceinline__ float red16(const float* v, int lane) {
    const bool b5 = lane & 32, b4 = lane & 16, b3 = lane & 8, b2 = lane & 4;
    float w8[8], w4[4], w2[2], w1;
    #pragma unroll
    for (int k = 0; k < 8; k++) {
        float t = b5 ? v[k] : v[k + 8];
        float o = __shfl_xor(t, 32, 64);
        w8[k] = (b5 ? v[k + 8] : v[k]) + o;
    }
    #pragma unroll
    for (int k = 0; k < 4; k++) {
        float t = b4 ? w8[k] : w8[k + 4];
        float o = __shfl_xor(t, 16, 64);
        w4[k] = (b4 ? w8[k + 4] : w8[k]) + o;
    }
    #pragma unroll
    for (int k = 0; k < 2; k++) {
        float t = b3 ? w4[k] : w4[k + 2];
        float o = __shfl_xor(t, 8, 64);
        w2[k] = (b3 ? w4[k + 2] : w4[k]) + o;
    }
    {
        float t = b2 ? w2[0] : w2[1];
        float o = __shfl_xor(t, 4, 64);
        w1 = (b2 ? w2[1] : w2[0]) + o;
    }
    w1 += __shfl_xor(w1, 2, 64);
    w1 += __shfl_xor(w1, 1, 64);
    return w1;   // d = lane>>2
}

__device__ __forceinline__ void st_rlx(float* p, float v) {
    __hip_atomic_store(p, v, __ATOMIC_RELAXED, __HIP_MEMORY_SCOPE_AGENT);
}
__device__ __forceinline__ float ld_rlx(const float* p) {
    return __hip_atomic_load(p, __ATOMIC_RELAXED, __HIP_MEMORY_SCOPE_AGENT);
}
__device__ __forceinline__ void st_rlx_u64(ull* p, ull v) {
    __hip_atomic_store(p, v, __ATOMIC_RELAXED, __HIP_MEMORY_SCOPE_AGENT);
}
__device__ __forceinline__ ull ld_rlx_u64(const ull* p) {
    return __hip_atomic_load(p, __ATOMIC_RELAXED, __HIP_MEMORY_SCOPE_AGENT);
}

__global__ __launch_bounds__(BLOCK)
void moe_loss_fused(const float* __restrict__ x, float* __restrict__ ws,
                    float* __restrict__ out) {
    const int tid  = threadIdx.x;
    const int b    = blockIdx.x;            // 16 consecutive blocks per layer
    const int wave = tid >> 6;
    const int lane = tid & 63;
    float* part = ws;
    ull* flags  = (ull*)(ws + FLAG_OFF);    // 192 x 8B

    // ---- phase 1: per-row softmax stats (1 row = 16 floats/thread) ----
    const float4* x4 = (const float4*)x;
    const int r4 = (b * BLOCK + tid) * 4;
    float v[DDIM]; float4 a4;
    a4 = x4[r4 + 0]; v[0]  = a4.x; v[1]  = a4.y; v[2]  = a4.z; v[3]  = a4.w;
    a4 = x4[r4 + 1]; v[4]  = a4.x; v[5]  = a4.y; v[6]  = a4.z; v[7]  = a4.w;
    a4 = x4[r4 + 2]; v[8]  = a4.x; v[9]  = a4.y; v[10] = a4.z; v[11] = a4.w;
    a4 = x4[r4 + 3]; v[12] = a4.x; v[13] = a4.y; v[14] = a4.z; v[15] = a4.w;

    float m = v[0];
    #pragma unroll
    for (int d = 1; d < DDIM; d++) m = fmaxf(m, v[d]);
    float e[DDIM], s = 0.f;
    #pragma unroll
    for (int d = 0; d < DDIM; d++) { e[d] = __expf(v[d] - m); s += e[d]; }
    const float inv = __frcp_rn(s);

    float p[DDIM], lq[DDIM], diag = 0.f;
    #pragma unroll
    for (int d = 0; d < DDIM; d++) {
        p[d]  = e[d] * inv;
        lq[d] = __logf(p[d] + 1e-9f);
        diag += p[d] * lq[d];
    }

    const float sp = red16(p,  lane);
    const float sl = red16(lq, lane);
    const float dg = wave_red6(diag);

    // ---- cross-wave combine -> value-major partials part[v*192 + b] ----
    __shared__ float lds[BLOCK / 64][PART];
    {
        const int g = lane >> 2, sub = lane & 3;
        if (sub == 0) lds[wave][g] = sp;
        if (sub == 1) lds[wave][DDIM + g] = sl;
        if (lane == 2) lds[wave][32] = dg;
    }
    __syncthreads();
    // wave 0 stores all 33 partials, drains ITS OWN vmcnt (stores acked
    // at the coherence point), then lane 0 publishes the 64-bit flag.
    if (wave == 0) {
        if (lane < PART) {
            const float val = lds[0][lane] + lds[1][lane]
                            + lds[2][lane] + lds[3][lane];
            st_rlx(&part[lane * NBLK + b], val);
        }
        asm volatile("s_waitcnt vmcnt(0)" ::: "memory");
        if (lane == 0) {
            const unsigned int seq = 0x5EED0000u ^ (unsigned int)b;
            st_rlx_u64(&flags[b], (ull)seq | ((ull)(~seq) << 32));
        }
    }

    if (b != 0) return;

    // ---- phase 2: block 0 waits on the 192 flags, then finalizes ----
    if (tid < NBLK) {
        const unsigned int seq = 0x5EED0000u ^ (unsigned int)tid;
        const ull expf64 = (ull)seq | ((ull)(~seq) << 32);
        int it = 0;
        while (ld_rlx_u64(&flags[tid]) != expf64) {
            if (++it > SPIN_CAP) break;     // degrade, never hang
            __builtin_amdgcn_s_sleep(1);
        }
    }
    __syncthreads();

    __shared__ float sP[LAYERS][DDIM];
    const int l = tid >> 4, d = tid & 15;
    float a = 0.f, bq = 0.f;
    if (tid < LAYERS * DDIM) {
        const float* pa = part + d * NBLK + l * BPL;
        const float* pb = part + (DDIM + d) * NBLK + l * BPL;
        #pragma unroll
        for (int k = 0; k < BPL; k++) {
            a  += ld_rlx(&pa[k]);
            bq += ld_rlx(&pb[k]);
        }
        sP[l][d] = a;
    }
    __syncthreads();
    float ce_v = 0.f, lg_v = 0.f;
    if (tid < LAYERS * DDIM) {
        float S = 0.f;
        #pragma unroll
        for (int d2 = 0; d2 < DDIM; d2++) S += sP[l][d2];
        ce_v = a * bq;                        // -> ce.sum()
        lg_v = __logf(a / S + 1e-8f);         // -> aux2 (pm = a/S)
    }
    const float dg_v = (tid < NBLK) ? ld_rlx(&part[32 * NBLK + tid]) : 0.f;

    __shared__ float red[3][BLOCK / 64];
    const float r0 = wave_red6(ce_v), r1 = wave_red6(lg_v), r2 = wave_red6(dg_v);
    if (lane == 0) { red[0][wave] = r0; red[1][wave] = r1; red[2][wave] = r2; }
    __syncthreads();
    if (tid == 0) {
        const float ce = red[0][0] + red[0][1] + red[0][2] + red[0][3];
        const float lg = red[1][0] + red[1][1] + red[1][2] + red[1][3];
        const float dgs = red[2][0] + red[2][1] + red[2][2] + red[2][3];
        const float aux1 = (ce - dgs) / (2.0f * LAYERS);
        const float aux2 = (-lg / (float)DDIM) / (float)LAYERS;
        out[0] = 0.01f * (1.0f * aux1 + aux2);
    }
}

extern "C" void kernel_launch(void* const* d_in, const int* in_sizes, int n_in,
                              void* d_out, int out_size, void* d_ws, size_t ws_size,
                              hipStream_t stream) {
    const float* noises = (const float*)d_in[0];
    float* ws  = (float*)d_ws;                  // ~27.2 KB used
    float* out = (float*)d_out;
    hipLaunchKernelGGL(moe_loss_fused, dim3(NBLK), dim3(BLOCK), 0, stream,
                       noises, ws, out);
}